// Round 1
// baseline (39.547 us; speedup 1.0000x reference)
//
#include <hip/hip_runtime.h>
#include <math.h>

#define BATCH 4096
#define KMAX 50
#define DIM 256

__global__ __launch_bounds__(256) void kv_memory_kernel(
    const int* __restrict__ keys,        // B*K
    const int* __restrict__ values,      // B*K
    const int* __restrict__ pair_len,    // B
    const float* __restrict__ query,     // B*D
    const float* __restrict__ key_table,   // NUM_KEYS*D
    const float* __restrict__ value_table, // NUM_VALUES*D
    float* __restrict__ out)             // B*D
{
    const int b    = blockIdx.x;
    const int tid  = threadIdx.x;
    const int lane = tid & 63;
    const int wave = tid >> 6;

    __shared__ int   s_keys[KMAX];
    __shared__ int   s_vals[KMAX];
    __shared__ float s_logit[64];
    __shared__ float s_prob[64];
    __shared__ float4 s_acc[4][64];

    int len = pair_len[b];
    if (len < 1) len = 1;
    if (len > KMAX) len = KMAX;

    if (tid < KMAX) {
        s_keys[tid] = keys[b * KMAX + tid];
        s_vals[tid] = values[b * KMAX + tid];
    }

    // Each lane owns 4 consecutive dims: d0 = lane*4
    const float4 q = *reinterpret_cast<const float4*>(query + (size_t)b * DIM + lane * 4);
    __syncthreads();

    // ---- Phase 1: logits. Wave w handles k = w, w+4, ... ----
    for (int k = wave; k < KMAX; k += 4) {
        float lg = -INFINITY;
        if (k < len) {  // wave-uniform branch
            const float4 kr = *reinterpret_cast<const float4*>(
                key_table + (size_t)s_keys[k] * DIM + lane * 4);
            float p = q.x * kr.x + q.y * kr.y + q.z * kr.z + q.w * kr.w;
            #pragma unroll
            for (int off = 32; off; off >>= 1) p += __shfl_xor(p, off);
            lg = p;
        }
        if (lane == 0) s_logit[k] = lg;
    }
    __syncthreads();

    // ---- Phase 2: softmax over len entries (wave 0 only, K=50 <= 64 lanes) ----
    if (wave == 0) {
        float lg = (lane < len) ? s_logit[lane] : -INFINITY;
        float m = lg;
        #pragma unroll
        for (int off = 32; off; off >>= 1) m = fmaxf(m, __shfl_xor(m, off));
        float e = (lane < len) ? __expf(lg - m) : 0.0f;
        float s = e;
        #pragma unroll
        for (int off = 32; off; off >>= 1) s += __shfl_xor(s, off);
        const float inv = 1.0f / s;
        if (lane < KMAX) s_prob[lane] = e * inv;
    }
    __syncthreads();

    // ---- Phase 3: weighted value sum. Wave w handles k = w, w+4, ... ----
    float4 acc = make_float4(0.f, 0.f, 0.f, 0.f);
    for (int k = wave; k < len; k += 4) {
        const float  p = s_prob[k];
        const float4 v = *reinterpret_cast<const float4*>(
            value_table + (size_t)s_vals[k] * DIM + lane * 4);
        acc.x += p * v.x;
        acc.y += p * v.y;
        acc.z += p * v.z;
        acc.w += p * v.w;
    }
    s_acc[wave][lane] = acc;
    __syncthreads();

    if (wave == 0) {
        float4 a0 = s_acc[0][lane];
        const float4 a1 = s_acc[1][lane];
        const float4 a2 = s_acc[2][lane];
        const float4 a3 = s_acc[3][lane];
        a0.x += a1.x + a2.x + a3.x;
        a0.y += a1.y + a2.y + a3.y;
        a0.z += a1.z + a2.z + a3.z;
        a0.w += a1.w + a2.w + a3.w;
        *reinterpret_cast<float4*>(out + (size_t)b * DIM + lane * 4) = a0;
    }
}

extern "C" void kernel_launch(void* const* d_in, const int* in_sizes, int n_in,
                              void* d_out, int out_size, void* d_ws, size_t ws_size,
                              hipStream_t stream) {
    const int*   keys        = (const int*)d_in[0];
    const int*   values      = (const int*)d_in[1];
    const int*   pair_len    = (const int*)d_in[2];
    const float* query       = (const float*)d_in[3];
    const float* key_table   = (const float*)d_in[4];
    const float* value_table = (const float*)d_in[5];
    float* out = (float*)d_out;

    kv_memory_kernel<<<BATCH, 256, 0, stream>>>(
        keys, values, pair_len, query, key_table, value_table, out);
}

// Round 2
// 36.639 us; speedup vs baseline: 1.0794x; 1.0794x over previous
//
#include <hip/hip_runtime.h>
#include <math.h>

#define BATCH 4096
#define KMAX 50
#define DIM 256
#define NITER 13   // ceil(50/4) + pad: every wave does 13 clamped iterations

__global__ __launch_bounds__(256) void kv_memory_kernel(
    const int* __restrict__ keys,          // B*K
    const int* __restrict__ values,        // B*K
    const int* __restrict__ pair_len,      // B
    const float* __restrict__ query,       // B*D
    const float* __restrict__ key_table,   // NUM_KEYS*D
    const float* __restrict__ value_table, // NUM_VALUES*D
    float* __restrict__ out)               // B*D
{
    const int b    = blockIdx.x;
    const int tid  = threadIdx.x;
    const int lane = tid & 63;
    const int wave = tid >> 6;

    __shared__ int    s_keys[KMAX];
    __shared__ int    s_vals[KMAX];
    __shared__ float  s_logit[64];     // k in [0,52) written; lanes >= len ignored
    __shared__ float4 s_acc[4][64];

    int len = pair_len[b];
    if (len < 1) len = 1;
    if (len > KMAX) len = KMAX;

    if (tid < KMAX) {
        s_keys[tid] = keys[b * KMAX + tid];
        s_vals[tid] = values[b * KMAX + tid];
    }

    // Each lane owns 4 consecutive dims: d0 = lane*4
    const float4 q = *reinterpret_cast<const float4*>(query + (size_t)b * DIM + lane * 4);
    __syncthreads();

    // ---- Phase 1: logits. Wave w handles k = w + 4*i, clamped to len-1 so all
    // 13 gathers issue unconditionally (dup rows are L1 hits). ----
    int kidx[NITER];
    #pragma unroll
    for (int i = 0; i < NITER; ++i) {
        const int k  = wave + 4 * i;
        const int kc = (k < len) ? k : (len - 1);
        kidx[i] = s_keys[kc];
    }
    float4 kr[NITER];
    #pragma unroll
    for (int i = 0; i < NITER; ++i) {
        kr[i] = *reinterpret_cast<const float4*>(
            key_table + (size_t)kidx[i] * DIM + lane * 4);
    }
    float dot[NITER];
    #pragma unroll
    for (int i = 0; i < NITER; ++i) {
        dot[i] = q.x * kr[i].x + q.y * kr[i].y + q.z * kr[i].z + q.w * kr[i].w;
    }
    // 13 independent butterfly chains, interleaved for ILP
    #pragma unroll
    for (int off = 32; off; off >>= 1) {
        #pragma unroll
        for (int i = 0; i < NITER; ++i) dot[i] += __shfl_xor(dot[i], off);
    }
    if (lane == 0) {
        #pragma unroll
        for (int i = 0; i < NITER; ++i) {
            const int k = wave + 4 * i;   // k < 52 < 64 always
            s_logit[k] = dot[i];
        }
    }
    __syncthreads();

    // ---- Phase 2: softmax, redundantly per wave (no extra barrier). ----
    float lg = (lane < len) ? s_logit[lane] : -INFINITY;
    float m = lg;
    #pragma unroll
    for (int off = 32; off; off >>= 1) m = fmaxf(m, __shfl_xor(m, off));
    float e = (lane < len) ? __expf(lg - m) : 0.0f;
    float s = e;
    #pragma unroll
    for (int off = 32; off; off >>= 1) s += __shfl_xor(s, off);
    const float p = e * (1.0f / s);   // p == 0 for lanes >= len

    // ---- Phase 3: weighted value sum, same clamped unrolled structure. ----
    int   vidx[NITER];
    float w[NITER];
    #pragma unroll
    for (int i = 0; i < NITER; ++i) {
        const int k  = wave + 4 * i;
        const int kc = (k < len) ? k : (len - 1);
        vidx[i] = s_vals[kc];
        w[i]    = __shfl(p, (k < 63) ? k : 63);   // lanes >= len hold p=0
    }
    float4 vr[NITER];
    #pragma unroll
    for (int i = 0; i < NITER; ++i) {
        vr[i] = *reinterpret_cast<const float4*>(
            value_table + (size_t)vidx[i] * DIM + lane * 4);
    }
    float4 acc = make_float4(0.f, 0.f, 0.f, 0.f);
    #pragma unroll
    for (int i = 0; i < NITER; ++i) {
        acc.x += w[i] * vr[i].x;
        acc.y += w[i] * vr[i].y;
        acc.z += w[i] * vr[i].z;
        acc.w += w[i] * vr[i].w;
    }
    s_acc[wave][lane] = acc;
    __syncthreads();

    if (wave == 0) {
        float4 a0 = s_acc[0][lane];
        const float4 a1 = s_acc[1][lane];
        const float4 a2 = s_acc[2][lane];
        const float4 a3 = s_acc[3][lane];
        a0.x += a1.x + a2.x + a3.x;
        a0.y += a1.y + a2.y + a3.y;
        a0.z += a1.z + a2.z + a3.z;
        a0.w += a1.w + a2.w + a3.w;
        *reinterpret_cast<float4*>(out + (size_t)b * DIM + lane * 4) = a0;
    }
}

extern "C" void kernel_launch(void* const* d_in, const int* in_sizes, int n_in,
                              void* d_out, int out_size, void* d_ws, size_t ws_size,
                              hipStream_t stream) {
    const int*   keys        = (const int*)d_in[0];
    const int*   values      = (const int*)d_in[1];
    const int*   pair_len    = (const int*)d_in[2];
    const float* query       = (const float*)d_in[3];
    const float* key_table   = (const float*)d_in[4];
    const float* value_table = (const float*)d_in[5];
    float* out = (float*)d_out;

    kv_memory_kernel<<<BATCH, 256, 0, stream>>>(
        keys, values, pair_len, query, key_table, value_table, out);
}